// Round 1
// baseline (143.100 us; speedup 1.0000x reference)
//
#include <hip/hip_runtime.h>
#include <stdint.h>

#define DM 1024
#define LS 2048
#define RMS_EPS 1.1920928955078125e-07f
#define S2 0.0029296875f   // BC_SCALE^2 = 3/1024, exact in fp32

typedef __attribute__((ext_vector_type(8))) short bf16x8;
typedef __attribute__((ext_vector_type(4))) float f32x4;

__device__ __forceinline__ unsigned short f2bf(float f) {
  uint32_t u = __builtin_bit_cast(uint32_t, f);
  u += 0x7FFFu + ((u >> 16) & 1u);   // round-to-nearest-even
  return (unsigned short)(u >> 16);
}

// ---------------------------------------------------------------------------
// K0: pack B (64x1024) and C (64x1024) fp32 -> stacked bf16 [128][1024]
// ---------------------------------------------------------------------------
__global__ __launch_bounds__(256) void k0_prep(const float* __restrict__ B,
                                               const float* __restrict__ C,
                                               unsigned short* __restrict__ Bbf) {
  int i4 = blockIdx.x * 256 + threadIdx.x;          // 0..32767 float4s
  const float4* src = (i4 < 16384) ? (const float4*)B : (const float4*)C;
  float4 v = src[i4 & 16383];
  ushort4 o;
  o.x = f2bf(v.x); o.y = f2bf(v.y); o.z = f2bf(v.z); o.w = f2bf(v.w);
  ((ushort4*)Bbf)[i4] = o;
}

// ---------------------------------------------------------------------------
// K1: BuCuT[b][l][128] = ([B;C] @ u[b])^T  via mfma_f32_16x16x32_bf16
// grid (64 l-tiles of 32, 4 b), block 256 (4 waves).
// Wave w handles rows 32w..32w+31 (2 row-tiles) x 2 col-tiles.
// A-frag: lane(m=lane&15,q=lane>>4) holds Bbf[row][k0+8q..+7]  (16B load)
// B-frag: lane(n=lane&15,q) holds bf16(u[k0+8q+j][col]), j=0..7
// C/D:    col=lane&15, row=4*(lane>>4)+reg  -> float4 store into [l][128]
// ---------------------------------------------------------------------------
__global__ __launch_bounds__(256) void k1_gemm(const float* __restrict__ u,
                                               const unsigned short* __restrict__ Bbf,
                                               float* __restrict__ BuCuT) {
  const int b  = blockIdx.y;
  const int l0 = blockIdx.x * 32;
  const int lane = threadIdx.x & 63;
  const int w    = threadIdx.x >> 6;
  const int n = lane & 15;
  const int q = lane >> 4;
  const float* ub = u + (size_t)b * DM * LS;

  f32x4 acc[2][2] = {};
  #pragma unroll 2
  for (int k0 = 0; k0 < DM; k0 += 32) {
    bf16x8 a[2], bb[2];
    #pragma unroll
    for (int rt = 0; rt < 2; ++rt) {
      int row = 32*w + 16*rt + n;
      a[rt] = *(const bf16x8*)(Bbf + (size_t)row * DM + k0 + 8*q);
    }
    #pragma unroll
    for (int ct = 0; ct < 2; ++ct) {
      int col = l0 + 16*ct + n;
      union { bf16x8 v; unsigned short s[8]; } t;
      #pragma unroll
      for (int j = 0; j < 8; ++j)
        t.s[j] = f2bf(ub[(size_t)(k0 + 8*q + j) * LS + col]);
      bb[ct] = t.v;
    }
    #pragma unroll
    for (int rt = 0; rt < 2; ++rt)
      #pragma unroll
      for (int ct = 0; ct < 2; ++ct)
        acc[rt][ct] = __builtin_amdgcn_mfma_f32_16x16x32_bf16(a[rt], bb[ct], acc[rt][ct], 0, 0, 0);
  }
  float* ob = BuCuT + (size_t)b * LS * 128;
  #pragma unroll
  for (int rt = 0; rt < 2; ++rt)
    #pragma unroll
    for (int ct = 0; ct < 2; ++ct) {
      int col = l0 + 16*ct + n;
      int row = 32*w + 16*rt + 4*q;
      *(f32x4*)(ob + (size_t)col * 128 + row) = acc[rt][ct];
    }
}

// ---------------------------------------------------------------------------
// K2: Kw[b][t][j] = S2 * sum_n Cu[n,t] * A[n]^j * Bu[n,t-j],  j=0..15
// grid (32 t-tiles of 64, 4 b), block 256. thread = (t-local = tid>>2, p=tid&3)
// covers n in [16p,16p+16). BuCuT rows: Bu = [0..64), Cu = [64..128).
// ---------------------------------------------------------------------------
__global__ __launch_bounds__(256) void k2_kw(const float* __restrict__ BuCuT,
                                             const float* __restrict__ A,
                                             float* __restrict__ Kw) {
  const int b  = blockIdx.y;
  const int t0 = blockIdx.x * 64;
  const int tl = threadIdx.x >> 2;
  const int p  = threadIdx.x & 3;
  const int t  = t0 + tl;
  const float* base = BuCuT + (size_t)b * LS * 128;

  float pw[16], aa[16];
  #pragma unroll
  for (int i = 0; i < 4; ++i) {
    float4 c4 = *(const float4*)(base + (size_t)t * 128 + 64 + 16*p + 4*i);
    float4 a4 = *(const float4*)(A + 16*p + 4*i);
    pw[4*i+0] = c4.x * S2; aa[4*i+0] = a4.x;
    pw[4*i+1] = c4.y * S2; aa[4*i+1] = a4.y;
    pw[4*i+2] = c4.z * S2; aa[4*i+2] = a4.z;
    pw[4*i+3] = c4.w * S2; aa[4*i+3] = a4.w;
  }
  float part[16];
  #pragma unroll
  for (int j = 0; j < 16; ++j) {
    float s = 0.f;
    if (t - j >= 0) {
      const float* bu = base + (size_t)(t - j) * 128 + 16*p;
      #pragma unroll
      for (int i = 0; i < 16; i += 4) {
        float4 b4 = *(const float4*)(bu + i);
        s = fmaf(pw[i+0], b4.x, s); s = fmaf(pw[i+1], b4.y, s);
        s = fmaf(pw[i+2], b4.z, s); s = fmaf(pw[i+3], b4.w, s);
      }
    }
    part[j] = s;
    #pragma unroll
    for (int i = 0; i < 16; ++i) pw[i] *= aa[i];   // pw = Cu*S2*A^j
  }
  __shared__ float ss[64][68];
  #pragma unroll
  for (int j = 0; j < 16; ++j) ss[tl][p*17 + j] = part[j];
  __syncthreads();
  const int o  = threadIdx.x * 4;     // 1024 outputs, 4 per thread
  const int t2 = o >> 4;
  const int j0 = o & 15;              // in {0,4,8,12}: never crosses a t row
  float4 r;
  r.x = ss[t2][j0+0] + ss[t2][17+j0+0] + ss[t2][34+j0+0] + ss[t2][51+j0+0];
  r.y = ss[t2][j0+1] + ss[t2][17+j0+1] + ss[t2][34+j0+1] + ss[t2][51+j0+1];
  r.z = ss[t2][j0+2] + ss[t2][17+j0+2] + ss[t2][34+j0+2] + ss[t2][51+j0+2];
  r.w = ss[t2][j0+3] + ss[t2][17+j0+3] + ss[t2][34+j0+3] + ss[t2][51+j0+3];
  *(float4*)(Kw + ((size_t)b * LS + t0 + t2) * 16 + j0) = r;
}

// ---------------------------------------------------------------------------
// K3: fused conv(W=16) + u*D skip + RMSNorm(d) + norm_w + store.
// grid (128 t-tiles of 16, 4 b), block 256.
// thread: tg=tid&3 -> 4 consecutive t, dr=tid>>2 -> d rows {dr+64c}.
// Kw in 64 VGPRs; y in 64 VGPRs until rsqrt known; aligned float4 window loads.
// ---------------------------------------------------------------------------
__global__ __launch_bounds__(256) void k3_conv(const float* __restrict__ u,
                                               const float* __restrict__ Kw,
                                               const float* __restrict__ Dv,
                                               const float* __restrict__ nw,
                                               float* __restrict__ out) {
  const int b  = blockIdx.y;
  const int t0 = blockIdx.x * 16;
  const int tg = threadIdx.x & 3;
  const int dr = threadIdx.x >> 2;
  const float* ub = u + (size_t)b * DM * LS;
  float* ob = out + (size_t)b * DM * LS;

  float kw[4][16];
  #pragma unroll
  for (int k = 0; k < 4; ++k) {
    const float* kp = Kw + ((size_t)b * LS + t0 + 4*tg + k) * 16;
    #pragma unroll
    for (int i = 0; i < 4; ++i) {
      float4 v = *(const float4*)(kp + 4*i);
      kw[k][4*i+0] = v.x; kw[k][4*i+1] = v.y; kw[k][4*i+2] = v.z; kw[k][4*i+3] = v.w;
    }
  }

  const int cbase = t0 - 16 + 4*tg;   // window start col (multiple of 4)
  float y[16][4];
  float ps[4] = {0.f, 0.f, 0.f, 0.f};
  #pragma unroll
  for (int c = 0; c < 16; ++c) {
    const int d = dr + 64*c;
    const float* row = ub + (size_t)d * LS;
    float wr[20];
    #pragma unroll
    for (int s5 = 0; s5 < 5; ++s5) {
      int g = cbase + 4*s5;
      float4 v;
      if (g >= 0) v = *(const float4*)(row + g);   // g<0 => whole f4 before t=0
      else        v = make_float4(0.f, 0.f, 0.f, 0.f);
      wr[4*s5+0] = v.x; wr[4*s5+1] = v.y; wr[4*s5+2] = v.z; wr[4*s5+3] = v.w;
    }
    const float Dd = Dv[d];
    #pragma unroll
    for (int k = 0; k < 4; ++k) {
      float acc = wr[16+k] * Dd;                   // skip connection u*D
      #pragma unroll
      for (int j = 0; j < 16; ++j)
        acc = fmaf(kw[k][j], wr[16 + k - j], acc); // indices 1..19, static
      y[c][k] = acc;
      ps[k] = fmaf(acc, acc, ps[k]);
    }
  }

  __shared__ float ss[16][68];
  #pragma unroll
  for (int k = 0; k < 4; ++k) ss[4*tg + k][dr] = ps[k];
  __syncthreads();
  __shared__ float rsq[16];
  if (threadIdx.x < 16) {
    float s = 0.f;
    #pragma unroll
    for (int i = 0; i < 16; ++i) {
      float4 v = *(const float4*)&ss[threadIdx.x][4*i];
      s += (v.x + v.y) + (v.z + v.w);
    }
    rsq[threadIdx.x] = rsqrtf(s * (1.f/1024.f) + RMS_EPS);
  }
  __syncthreads();
  float rq[4];
  #pragma unroll
  for (int k = 0; k < 4; ++k) rq[k] = rsq[4*tg + k];
  #pragma unroll
  for (int c = 0; c < 16; ++c) {
    const int d = dr + 64*c;
    const float wn = nw[d];
    float4 o;
    o.x = y[c][0] * rq[0] * wn;
    o.y = y[c][1] * rq[1] * wn;
    o.z = y[c][2] * rq[2] * wn;
    o.w = y[c][3] * rq[3] * wn;
    *(float4*)(ob + (size_t)d * LS + t0 + 4*tg) = o;
  }
}

// ---------------------------------------------------------------------------
extern "C" void kernel_launch(void* const* d_in, const int* in_sizes, int n_in,
                              void* d_out, int out_size, void* d_ws, size_t ws_size,
                              hipStream_t stream) {
  // inputs: [0]=L(int,1), [1]=u, [2]=A, [3]=B, [4]=C, [5]=D, [6]=norm_w
  const float* u  = (const float*)d_in[1];
  const float* A  = (const float*)d_in[2];
  const float* B  = (const float*)d_in[3];
  const float* C  = (const float*)d_in[4];
  const float* Dv = (const float*)d_in[5];
  const float* nw = (const float*)d_in[6];
  float* out = (float*)d_out;

  // workspace carve (4.75 MB total)
  float* BuCuT = (float*)d_ws;                                          // 4 MB
  float* Kw    = (float*)((char*)d_ws + (4u << 20));                    // 512 KB
  unsigned short* Bbf = (unsigned short*)((char*)d_ws + (4u << 20) + (512u << 10)); // 256 KB

  k0_prep<<<dim3(128),    dim3(256), 0, stream>>>(B, C, Bbf);
  k1_gemm<<<dim3(64, 4),  dim3(256), 0, stream>>>(u, Bbf, BuCuT);
  k2_kw  <<<dim3(32, 4),  dim3(256), 0, stream>>>(BuCuT, A, Kw);
  k3_conv<<<dim3(128, 4), dim3(256), 0, stream>>>(u, Kw, Dv, nw, out);
}